// Round 2
// baseline (11.441 us; speedup 1.0000x reference)
//
#include <hip/hip_runtime.h>

#define N_LAYERS 32
#define SEL_K 24
#define N_CHOICES 9   // N_LAYERS - SEL_K + 1
#define BATCH 32
#define DIM 4096
#define G_EPS 1e-10f
#define CHUNKS 48     // blocks per batch row; each block copies half a feature row

typedef float vfloat4 __attribute__((ext_vector_type(4)));

__global__ __launch_bounds__(256) void layer_selector_kernel(
    const float* __restrict__ feat,    // [B, L, D]
    const float* __restrict__ logits,  // [N_CHOICES]
    const float* __restrict__ noise,   // [B, N_CHOICES]
    float* __restrict__ out)           // [B*SEL_K*D] selected ++ [B*N_CHOICES] probs
{
    const int blk = blockIdx.x;
    const int b = blk / CHUNKS;
    const int chunk = blk % CHUNKS;

    // Redundant per-thread gumbel-softmax over 9 choices: pure VALU on an idle
    // pipe; removes LDS + __syncthreads serialization (waves run independently).
    // b is block-uniform -> noise/logits loads scalarize to s_load broadcasts.
    float x[N_CHOICES];
    float m = -1e30f;
    #pragma unroll
    for (int c = 0; c < N_CHOICES; ++c) {
        float u = noise[b * N_CHOICES + c];
        float g = -logf(-logf(u + G_EPS) + G_EPS);
        x[c] = logits[c] + g;            // tau = 1.0
        m = fmaxf(m, x[c]);
    }
    float sum = 0.f;
    #pragma unroll
    for (int c = 0; c < N_CHOICES; ++c) {
        x[c] = expf(x[c] - m);           // jax.nn.softmax numerics: exp(x - max)
        sum += x[c];
    }
    int idx = 0;
    float best = -1.f;
    #pragma unroll
    for (int c = 0; c < N_CHOICES; ++c) {
        float y = x[c] / sum;            // y_soft
        if (y > best) { best = y; idx = c; }   // strict > == first-occurrence argmax
    }
    const float p = (1.0f + best) - best;      // y_hard + y_soft - y_soft at argmax

    // Scaled half-row copy: selected[b,k,:] = p * feat[b, idx+k, :]
    const int k = chunk >> 1;
    const int col4 = (chunk & 1) * (DIM / 8);  // 512 float4 per half-row

    const vfloat4* __restrict__ src =
        (const vfloat4*)(feat + ((size_t)b * N_LAYERS + (size_t)(idx + k)) * DIM) + col4;
    vfloat4* __restrict__ dst =
        (vfloat4*)(out + ((size_t)b * SEL_K + (size_t)k) * DIM) + col4;

    #pragma unroll
    for (int i = threadIdx.x; i < DIM / 8; i += 256) {
        vfloat4 v = src[i];
        v *= p;
        // Streamed output, never re-read by this kernel: bypass L2 so the
        // feature working set stays hot across graph replays.
        __builtin_nontemporal_store(v, &dst[i]);
    }

    // One block per b (chunk==0) writes the selection_probs output tail.
    if (chunk == 0 && threadIdx.x < N_CHOICES) {
        const int c = threadIdx.x;
        out[(size_t)BATCH * SEL_K * DIM + (size_t)b * N_CHOICES + c] =
            (c == idx) ? p : 0.0f;       // exactly 0 elsewhere: (0+s)-s == 0
    }
}

extern "C" void kernel_launch(void* const* d_in, const int* in_sizes, int n_in,
                              void* d_out, int out_size, void* d_ws, size_t ws_size,
                              hipStream_t stream) {
    const float* feat   = (const float*)d_in[0];  // (32, 32, 4096) f32
    const float* logits = (const float*)d_in[1];  // (9,) f32
    const float* noise  = (const float*)d_in[2];  // (32, 9) f32
    float* out = (float*)d_out;

    dim3 grid(BATCH * CHUNKS);   // 1536 blocks = 6/CU
    dim3 block(256);
    hipLaunchKernelGGL(layer_selector_kernel, grid, block, 0, stream,
                       feat, logits, noise, out);
}